// Round 5
// baseline (499.798 us; speedup 1.0000x reference)
//
#include <hip/hip_runtime.h>
#include <hip/hip_bf16.h>
#include <stdint.h>

#define B_ 256
#define T_ 512
#define V_ 30000
#define E_ 256
#define H_ 32

#define SEG 32
#define NSEG (T_ / SEG)

typedef float v2f __attribute__((ext_vector_type(2)));
typedef unsigned int uint2e __attribute__((ext_vector_type(2)));

#define LOG2E_F 1.44269504088896340736f

// ---------------------------------------------------------------------------
// Raw-ISA helpers
// ---------------------------------------------------------------------------
__device__ __forceinline__ float exp2_fast(float x) {      // 2^x
    float r; asm("v_exp_f32 %0, %1" : "=v"(r) : "v"(x)); return r;
}
__device__ __forceinline__ float rcp_fast(float x) {       // 1/x
    float r; asm("v_rcp_f32 %0, %1" : "=v"(r) : "v"(x)); return r;
}
// packed fp32 FMA, all-VGPR operands: acc.{lo,hi} += w.{lo,hi} * h.{lo,hi}
__device__ __forceinline__ void pk_fma(v2f& acc, v2f w, v2f h) {
    asm("v_pk_fma_f32 %0, %1, %2, %0" : "+v"(acc) : "v"(w), "v"(h));
}
// DPP lane-permute move (XOR patterns only -> direction-unambiguous)
template <int CTRL>
__device__ __forceinline__ float mdpp(float x) {
    return __int_as_float(
        __builtin_amdgcn_mov_dpp(__float_as_int(x), CTRL, 0xF, 0xF, true));
}
#define DPP_XOR1  0xB1   // quad_perm [1,0,3,2]
#define DPP_XOR2  0x4E   // quad_perm [2,3,0,1]
#define DPP_XOR3  0x1B   // quad_perm [3,2,1,0]
#define DPP_XOR7  0x141  // row_half_mirror  (i -> i^7 within 8)
#define DPP_XOR15 0x140  // row_mirror       (i -> i^15 within 16)

// value of x at lane (l ^ 32); xor-fold makes it hw-convention independent
__device__ __forceinline__ float swap32(float x) {
    uint2e r = __builtin_amdgcn_permlane32_swap(
        __float_as_uint(x), __float_as_uint(x), false, false);
    return __uint_as_float(r.x ^ r.y ^ __float_as_uint(x));
}
// value of x at lane (l ^ 16)
__device__ __forceinline__ float swap16(float x) {
    uint2e r = __builtin_amdgcn_permlane16_swap(
        __float_as_uint(x), __float_as_uint(x), false, false);
    return __uint_as_float(r.x ^ r.y ^ __float_as_uint(x));
}

// ---------------------------------------------------------------------------
// GEMM: Out[M,192] = (A[M,K] @ Wcat[192,K]^T + bias) * gate_scale
// gate_scale folds the exp->exp2 conversion: r,z gates * -log2e ; n * +2log2e
// ---------------------------------------------------------------------------
#define GEMM_MT 64
#define GEMM_KC 32
#define GEMM_PA 68
#define GEMM_PB 196

__global__ __launch_bounds__(256) void gemm_gates(
    const float* __restrict__ A, int M, int K,
    const float* __restrict__ Wf, const float* __restrict__ Wb,
    const float* __restrict__ bihf, const float* __restrict__ bhhf,
    const float* __restrict__ bihb, const float* __restrict__ bhhb,
    float* __restrict__ Out)
{
    __shared__ float As[GEMM_KC][GEMM_PA];
    __shared__ float Bs[GEMM_KC][GEMM_PB];

    const int tid = threadIdx.x;
    const int mbase = blockIdx.x * GEMM_MT;
    const int mg = tid >> 5, ng = tid & 31;
    const int m_off = mg * 8, n_off = ng * 6;

    float acc[8][6];
    #pragma unroll
    for (int r = 0; r < 8; ++r)
        #pragma unroll
        for (int c = 0; c < 6; ++c) acc[r][c] = 0.f;

    for (int kc = 0; kc < K; kc += GEMM_KC) {
        #pragma unroll
        for (int i = 0; i < 2; ++i) {
            int fi = tid + 256 * i;
            int row = fi >> 3, cf = fi & 7;
            int m = mbase + row;
            float4 v = make_float4(0.f, 0.f, 0.f, 0.f);
            if (m < M) v = *(const float4*)&A[(size_t)m * K + kc + cf * 4];
            As[cf * 4 + 0][row] = v.x; As[cf * 4 + 1][row] = v.y;
            As[cf * 4 + 2][row] = v.z; As[cf * 4 + 3][row] = v.w;
        }
        #pragma unroll
        for (int i = 0; i < 6; ++i) {
            int fi = tid + 256 * i;
            int g = fi >> 3, cf = fi & 7;
            const float* Wsel = (g < 96) ? (Wf + (size_t)g * K)
                                         : (Wb + (size_t)(g - 96) * K);
            float4 v = *(const float4*)&Wsel[kc + cf * 4];
            Bs[cf * 4 + 0][g] = v.x; Bs[cf * 4 + 1][g] = v.y;
            Bs[cf * 4 + 2][g] = v.z; Bs[cf * 4 + 3][g] = v.w;
        }
        __syncthreads();
        #pragma unroll
        for (int k = 0; k < GEMM_KC; ++k) {
            float a[8], bb[6];
            *(float4*)&a[0] = *(const float4*)&As[k][m_off];
            *(float4*)&a[4] = *(const float4*)&As[k][m_off + 4];
            *(float2*)&bb[0] = *(const float2*)&Bs[k][n_off];
            *(float2*)&bb[2] = *(const float2*)&Bs[k][n_off + 2];
            *(float2*)&bb[4] = *(const float2*)&Bs[k][n_off + 4];
            #pragma unroll
            for (int r = 0; r < 8; ++r)
                #pragma unroll
                for (int c = 0; c < 6; ++c)
                    acc[r][c] = fmaf(a[r], bb[c], acc[r][c]);
        }
        __syncthreads();
    }

    float bias[6], gsc[6];
    #pragma unroll
    for (int c = 0; c < 6; ++c) {
        int g = n_off + c;
        int g96 = (g < 96) ? g : g - 96;
        const float* bih = (g < 96) ? bihf : bihb;
        const float* bhh = (g < 96) ? bhhf : bhhb;
        bias[c] = bih[g96] + ((g96 < 64) ? bhh[g96] : 0.f);
        gsc[c]  = (g96 < 64) ? -LOG2E_F : 2.0f * LOG2E_F;
    }
    #pragma unroll
    for (int r = 0; r < 8; ++r) {
        int m = mbase + m_off + r;
        if (m < M) {
            float* op = &Out[(size_t)m * 192 + n_off];
            #pragma unroll
            for (int c = 0; c < 6; ++c) op[c] = (acc[r][c] + bias[c]) * gsc[c];
        }
    }
}

// ---------------------------------------------------------------------------
// GRU scan, K-split layout + LDS-STAGED gi.
// r0-r4 post-mortems: per-step stall ~550-600cy was constant across four
// broadcast variants -> not the h-path. Suspect: the 3 per-step global gi
// loads' s_waitcnt exposing L2-miss/HBM latency (G0=23MB, gi1=100MB, both
// beyond per-XCD L2) every step. Fix: NO global loads in the step loop.
//
// Segments of 32 steps, double-buffered in LDS:
//   g_lds[2][32][96]: per step the 96 floats gi[row][dir*96 .. +96).
//   Staged per segment by 12 coalesced float4 loads/lane, bulk-issued one
//   full segment (~32 steps) before their single drain point -> zero wait.
//   Step loop reads 3 broadcast ds_read_b32 (prefetched 1 step ahead,
//   conflict-free: lanes l and l^32 read the same address).
// Mask: per-segment 32-bit ballot -> SGPR bitmask, 1 SALU/step, no loads.
// K2's vocab rows stage through row_lds (pipelined 2 segments ahead).
// Compute core identical to r4: K-split rows [L,H,L,H] (lane l & l^32 do
// complementary k-halves of the same unit -> 48 weight VGPRs), seed via
// permlane16_swap, 15-op DPP XOR-butterfly, 24 pk_fma, permlane32_swap
// combine, exp2/rcp activations with log2e pre-folded.
// ---------------------------------------------------------------------------
template <int USE_IDS>
__global__ __launch_bounds__(64, 1)
__attribute__((amdgpu_waves_per_eu(1, 1)))
void gru_scan(
    const float* __restrict__ gi,     // [rows,192]: G0 (gather) or gi1 (direct)
    const int* __restrict__ ids,
    const int* __restrict__ mask,
    const float* __restrict__ Whh_f, const float* __restrict__ Whh_b,
    const float* __restrict__ bhh_f, const float* __restrict__ bhh_b,
    float* __restrict__ out_seq,      // [B,T,64] or nullptr
    float* __restrict__ out_fin)      // [B,64]   or nullptr
{
    __shared__ float g_lds[2][SEG][96];   // 24 KB
    __shared__ int   row_lds[2][SEG];     // 256 B (used by USE_IDS only)

    const int l = threadIdx.x;
    const int i16 = l & 15;
    const int row = l >> 4;
    const int hi = row & 1;               // unit half
    const int kh = row >> 1;              // k half this lane computes
    const int j = i16 + 16 * hi;          // this lane's unit
    const bool lower = l < 32;            // lanes 0-31: j == l
    const bool self_seed = (hi == kh);    // rows 0,3 own their k-half seed
    const int dir = blockIdx.x & 1;
    const int b = blockIdx.x >> 1;
    const int bT = b * T_;

    const float* Whh = dir ? Whh_b : Whh_f;
    const float* bhh = dir ? bhh_b : bhh_f;

    const float sRZ = -LOG2E_F;
    const float sN2 = 2.0f * LOG2E_F;

    // butterfly value order: pair q holds seed[i16^M0[q]], seed[i16^M1[q]]
    const int M0[8] = {0, 2, 7, 5, 15, 13, 8, 10};
    const int M1[8] = {1, 3, 6, 4, 14, 12, 9, 11};

    v2f wR[8], wZ[8], wN[8];
    #pragma unroll
    for (int q = 0; q < 8; ++q) {
        const int c0 = kh * 16 + (i16 ^ M0[q]);
        const int c1 = kh * 16 + (i16 ^ M1[q]);
        wR[q] = (v2f){Whh[j * 32 + c0] * sRZ, Whh[j * 32 + c1] * sRZ};
        wZ[q] = (v2f){Whh[(32 + j) * 32 + c0] * sRZ,
                      Whh[(32 + j) * 32 + c1] * sRZ};
        wN[q] = (v2f){Whh[(64 + j) * 32 + c0] * sN2,
                      Whh[(64 + j) * 32 + c1] * sN2};
    }
    float bns = bhh[64 + j] * sN2;

    // PIN: opaque asm keeps the 48 weight regs loop-resident (no remat).
    #pragma unroll
    for (int q = 0; q < 8; ++q)
        asm volatile("" : "+v"(wR[q]), "+v"(wZ[q]), "+v"(wN[q]));
    asm volatile("" : "+v"(bns));

    // logical step n = 0..511 maps to time t = dir ? T-1-n : n
    auto t_of = [&](int n) { return dir ? (T_ - 1 - n) : n; };

    // ---- prologue: stage masks+rows for seg 0,1; gi for seg 0 ----
    uint32_t mseg_cur, mseg_nx1, mseg_nx2 = 0;
    {
        int mk0 = 0, mk1 = 0, rm0 = 0, rm1 = 0;
        if (lower) {
            const int ga0 = bT + t_of(l);
            const int ga1 = bT + t_of(SEG + l);
            mk0 = mask[ga0];
            mk1 = mask[ga1];
            if (USE_IDS) { rm0 = ids[ga0]; rm1 = ids[ga1]; }
            else         { rm0 = ga0;      rm1 = ga1;      }
        }
        mseg_cur = (uint32_t)__ballot(lower && (mk0 != 0));
        mseg_nx1 = (uint32_t)__ballot(lower && (mk1 != 0));
        if (lower) { row_lds[0][l] = rm0; row_lds[1][l] = rm1; }

        #pragma unroll
        for (int i = 0; i < 12; ++i) {
            const int f = l + 64 * i;
            const int su = f / 24;
            const int o4 = (f % 24) * 4;
            const int rown = row_lds[0][su];   // resolved row (id or bT+t)
            float4 v = *(const float4*)&gi[(size_t)rown * 192 + dir * 96 + o4];
            *(float4*)&g_lds[0][su][o4] = v;
        }
    }
    float cR = g_lds[0][0][j];
    float cZ = g_lds[0][0][32 + j];
    float cN = g_lds[0][0][64 + j];

    float h = 0.f;

    for (int s = 0; s < NSEG; ++s) {
        const int buf = s & 1;

        // --- A: issue mask/row global loads for segment s+2 (lanes 0-31)
        int mk_r = 0, rm_r = 0;
        if (s < NSEG - 2 && lower) {
            const int ga = bT + t_of(SEG * (s + 2) + l);
            mk_r = mask[ga];
            if (USE_IDS) rm_r = ids[ga];
            else         rm_r = ga;
        }

        // --- B: issue 12 gi float4 loads for segment s+1 (drained at D)
        float4 gv[12];
        if (s < NSEG - 1) {
            #pragma unroll
            for (int i = 0; i < 12; ++i) {
                const int f = l + 64 * i;
                const int su = f / 24;
                const int o4 = (f % 24) * 4;
                int rown;
                if (USE_IDS) rown = row_lds[buf ^ 1][su];
                else         rown = bT + t_of(SEG * (s + 1) + su);
                gv[i] = *(const float4*)&gi[(size_t)rown * 192 + dir * 96 + o4];
            }
        }
        // keep the A/B loads in flight across the compute phase
        asm volatile("" ::: "memory");

        // --- C: 32 steps, DS-pipe only
        const uint32_t mseg = mseg_cur;
        for (int su4 = 0; su4 < 8; ++su4) {
            #pragma unroll
            for (int u = 0; u < 4; ++u) {
                const int su = su4 * 4 + u;
                // prefetch next step's gi (dummy re-read of 31 at seg end)
                const int sup = (su + 1 <= 31) ? (su + 1) : 31;
                const float nR = g_lds[buf][sup][j];
                const float nZ = g_lds[buf][sup][32 + j];
                const float nN = g_lds[buf][sup][64 + j];

                // seed = h of (kh*16 + i16): rows 0,3 self; rows 1,2 from l^16
                const float hx = swap16(h);
                const float seed = self_seed ? h : hx;

                // distribute 16 seed values within the row (15 DPP movs)
                v2f p[8];
                p[0].x = seed;                      p[0].y = mdpp<DPP_XOR1>(seed);
                p[1].x = mdpp<DPP_XOR2>(seed);      p[1].y = mdpp<DPP_XOR3>(seed);
                p[2].x = mdpp<DPP_XOR7>(seed);      p[2].y = mdpp<DPP_XOR7>(p[0].y);
                p[3].x = mdpp<DPP_XOR7>(p[1].x);    p[3].y = mdpp<DPP_XOR7>(p[1].y);
                p[4].x = mdpp<DPP_XOR15>(seed);     p[4].y = mdpp<DPP_XOR15>(p[0].y);
                p[5].x = mdpp<DPP_XOR15>(p[1].x);   p[5].y = mdpp<DPP_XOR15>(p[1].y);
                p[6].x = mdpp<DPP_XOR15>(p[2].x);   p[6].y = mdpp<DPP_XOR15>(p[2].y);
                p[7].x = mdpp<DPP_XOR15>(p[3].x);   p[7].y = mdpp<DPP_XOR15>(p[3].y);

                // half-K matvec: 3 independent depth-8 pk_fma chains
                v2f aR = {0.f, 0.f}, aZ = {0.f, 0.f}, aN = {0.f, 0.f};
                #pragma unroll
                for (int q = 0; q < 8; ++q) {
                    pk_fma(aR, wR[q], p[q]);
                    pk_fma(aZ, wZ[q], p[q]);
                    pk_fma(aN, wN[q], p[q]);
                }
                // combine k-halves: lane l^32 has same unit, other half
                const float sR = aR.x + aR.y;
                const float sZ = aZ.x + aZ.y;
                const float sN = aN.x + aN.y;
                const float SR = sR + swap32(sR);
                const float SZ = sZ + swap32(sZ);
                const float SN = sN + swap32(sN);

                const float yr  = cR + SR;
                const float yz  = cZ + SZ;
                const float hns = bns + SN;
                const float r = rcp_fast(1.0f + exp2_fast(yr));
                const float z = rcp_fast(1.0f + exp2_fast(yz));
                const float yn = cN + r * hns;
                const float n = fmaf(-2.0f, rcp_fast(1.0f + exp2_fast(yn)), 1.0f);
                const float hnew = n + z * (h - n);      // (1-z)n + z h
                const bool mm = (mseg >> su) & 1u;
                h = mm ? hnew : h;                       // packed-seq freeze

                if (out_seq != nullptr && lower) {
                    const int t = t_of(SEG * s + su);
                    out_seq[(size_t)(bT + t) * 64 + dir * 32 + j] = h;
                }
                cR = nR; cZ = nZ; cN = nN;
            }
        }

        // --- D: drain (loads are ~32 steps old -> free) and commit to LDS
        if (s < NSEG - 1) {
            #pragma unroll
            for (int i = 0; i < 12; ++i) {
                const int f = l + 64 * i;
                const int su = f / 24;
                const int o4 = (f % 24) * 4;
                *(float4*)&g_lds[buf ^ 1][su][o4] = gv[i];
            }
        }
        if (s < NSEG - 2) {
            mseg_nx2 = (uint32_t)__ballot(lower && (mk_r != 0));
            if (lower) row_lds[buf][l] = rm_r;
        }
        mseg_cur = mseg_nx1; mseg_nx1 = mseg_nx2;

        // cross-segment prefetch of step 0 (after the D writes above)
        if (s < NSEG - 1) {
            cR = g_lds[buf ^ 1][0][j];
            cZ = g_lds[buf ^ 1][0][32 + j];
            cN = g_lds[buf ^ 1][0][64 + j];
        }
    }

    if (out_fin != nullptr && lower)
        out_fin[b * 64 + dir * 32 + j] = h;
}

// ---------------------------------------------------------------------------
// Head: out[b,o] = hfin[b,:] . Wout[o,:] + bout[o]
// ---------------------------------------------------------------------------
__global__ void head_kernel(const float* __restrict__ hfin,
                            const float* __restrict__ Wout,
                            const float* __restrict__ bout,
                            float* __restrict__ out)
{
    int idx = blockIdx.x * blockDim.x + threadIdx.x;
    if (idx >= B_ * 6) return;
    int b = idx / 6, o = idx % 6;
    float acc = bout[o];
    const float* hp = hfin + b * 64;
    const float* wp = Wout + o * 64;
    #pragma unroll
    for (int k = 0; k < 64; ++k) acc = fmaf(hp[k], wp[k], acc);
    out[idx] = acc;
}

// ---------------------------------------------------------------------------
extern "C" void kernel_launch(void* const* d_in, const int* in_sizes, int n_in,
                              void* d_out, int out_size, void* d_ws, size_t ws_size,
                              hipStream_t stream)
{
    const int*   ids   = (const int*)d_in[0];
    const int*   mask  = (const int*)d_in[1];
    const float* embed = (const float*)d_in[2];
    const float* Wih0f = (const float*)d_in[3];
    const float* Whh0f = (const float*)d_in[4];
    const float* bih0f = (const float*)d_in[5];
    const float* bhh0f = (const float*)d_in[6];
    const float* Wih0b = (const float*)d_in[7];
    const float* Whh0b = (const float*)d_in[8];
    const float* bih0b = (const float*)d_in[9];
    const float* bhh0b = (const float*)d_in[10];
    const float* Wih1f = (const float*)d_in[11];
    const float* Whh1f = (const float*)d_in[12];
    const float* bih1f = (const float*)d_in[13];
    const float* bhh1f = (const float*)d_in[14];
    const float* Wih1b = (const float*)d_in[15];
    const float* Whh1b = (const float*)d_in[16];
    const float* bih1b = (const float*)d_in[17];
    const float* bhh1b = (const float*)d_in[18];
    const float* Wout  = (const float*)d_in[19];
    const float* bout  = (const float*)d_in[20];

    // workspace layout (floats):
    //   gbuf : G0 [V,192] (K1,K2) then gi1 [B*T,192] (K3,K4)
    //   x1   : [B,T,64]
    //   hfin : [B,64]
    float* ws   = (float*)d_ws;
    float* gbuf = ws;
    float* x1   = ws + (size_t)B_ * T_ * 192;
    float* hfin = x1 + (size_t)B_ * T_ * 64;

    // K1: vocab-factored layer-0 input gates  G0 = (embed @ Wcat0^T + b) * gsc
    gemm_gates<<<(V_ + GEMM_MT - 1) / GEMM_MT, 256, 0, stream>>>(
        embed, V_, E_, Wih0f, Wih0b, bih0f, bhh0f, bih0b, bhh0b, gbuf);

    // K2: layer-0 bidirectional scan (gathers G0[id]), writes x1
    gru_scan<1><<<2 * B_, 64, 0, stream>>>(
        gbuf, ids, mask, Whh0f, Whh0b, bhh0f, bhh0b, x1, nullptr);

    // K3: layer-1 input gates  gi1 = (x1 @ Wcat1^T + b) * gsc
    gemm_gates<<<(B_ * T_) / GEMM_MT, 256, 0, stream>>>(
        x1, B_ * T_, 64, Wih1f, Wih1b, bih1f, bhh1f, bih1b, bhh1b, gbuf);

    // K4: layer-1 scan, final hiddens only
    gru_scan<0><<<2 * B_, 64, 0, stream>>>(
        gbuf, nullptr, mask, Whh1f, Whh1b, bhh1f, bhh1b, nullptr, hfin);

    // K5: output head
    head_kernel<<<(B_ * 6 + 255) / 256, 256, 0, stream>>>(hfin, Wout, bout,
                                                          (float*)d_out);
}

// Round 7
// 483.968 us; speedup vs baseline: 1.0327x; 1.0327x over previous
//
#include <hip/hip_runtime.h>
#include <hip/hip_bf16.h>
#include <stdint.h>

#define B_ 256
#define T_ 512
#define V_ 30000
#define E_ 256
#define H_ 32

typedef float v2f __attribute__((ext_vector_type(2)));
typedef unsigned int uint2e __attribute__((ext_vector_type(2)));

#define LOG2E_F 1.44269504088896340736f

// ---------------------------------------------------------------------------
// Raw-ISA helpers
// ---------------------------------------------------------------------------
__device__ __forceinline__ float exp2_fast(float x) {      // 2^x
    float r; asm("v_exp_f32 %0, %1" : "=v"(r) : "v"(x)); return r;
}
__device__ __forceinline__ float rcp_fast(float x) {       // 1/x
    float r; asm("v_rcp_f32 %0, %1" : "=v"(r) : "v"(x)); return r;
}
// packed fp32 FMA, all-VGPR operands: acc.{lo,hi} += w.{lo,hi} * h.{lo,hi}
__device__ __forceinline__ void pk_fma(v2f& acc, v2f w, v2f h) {
    asm("v_pk_fma_f32 %0, %1, %2, %0" : "+v"(acc) : "v"(w), "v"(h));
}
// DPP lane-permute move (XOR patterns only -> direction-unambiguous)
template <int CTRL>
__device__ __forceinline__ float mdpp(float x) {
    return __int_as_float(
        __builtin_amdgcn_mov_dpp(__float_as_int(x), CTRL, 0xF, 0xF, true));
}
#define DPP_XOR1  0xB1   // quad_perm [1,0,3,2]
#define DPP_XOR2  0x4E   // quad_perm [2,3,0,1]
#define DPP_XOR3  0x1B   // quad_perm [3,2,1,0]
#define DPP_XOR7  0x141  // row_half_mirror  (i -> i^7 within 8)
#define DPP_XOR15 0x140  // row_mirror       (i -> i^15 within 16)

// x[l] + x[l^32]: permlane32_swap(x,x) yields the pair {x[l], x[l^32]} per
// lane (hw-convention independent as a multiset) -> sum is exact and order-
// free (IEEE add commutative). Removes the 2-xor fold from the spine.
__device__ __forceinline__ float xsum32(float x) {
    uint2e r = __builtin_amdgcn_permlane32_swap(
        __float_as_uint(x), __float_as_uint(x), false, false);
    return __uint_as_float(r.x) + __uint_as_float(r.y);
}
// value of x at lane (l ^ 16): needs the exact swapped value -> xor-fold
// (v_xor3_b32, exact bitwise selection from the {self,swapped} pair)
__device__ __forceinline__ float swap16(float x) {
    uint2e r = __builtin_amdgcn_permlane16_swap(
        __float_as_uint(x), __float_as_uint(x), false, false);
    return __uint_as_float(r.x ^ r.y ^ __float_as_uint(x));
}

// ---------------------------------------------------------------------------
// GEMM: Out[M,192] = (A[M,K] @ Wcat[192,K]^T + bias) * gate_scale
// gate_scale folds the exp->exp2 conversion: r,z gates * -log2e ; n * +2log2e
// ---------------------------------------------------------------------------
#define GEMM_MT 64
#define GEMM_KC 32
#define GEMM_PA 68
#define GEMM_PB 196

__global__ __launch_bounds__(256) void gemm_gates(
    const float* __restrict__ A, int M, int K,
    const float* __restrict__ Wf, const float* __restrict__ Wb,
    const float* __restrict__ bihf, const float* __restrict__ bhhf,
    const float* __restrict__ bihb, const float* __restrict__ bhhb,
    float* __restrict__ Out)
{
    __shared__ float As[GEMM_KC][GEMM_PA];
    __shared__ float Bs[GEMM_KC][GEMM_PB];

    const int tid = threadIdx.x;
    const int mbase = blockIdx.x * GEMM_MT;
    const int mg = tid >> 5, ng = tid & 31;
    const int m_off = mg * 8, n_off = ng * 6;

    float acc[8][6];
    #pragma unroll
    for (int r = 0; r < 8; ++r)
        #pragma unroll
        for (int c = 0; c < 6; ++c) acc[r][c] = 0.f;

    for (int kc = 0; kc < K; kc += GEMM_KC) {
        #pragma unroll
        for (int i = 0; i < 2; ++i) {
            int fi = tid + 256 * i;
            int row = fi >> 3, cf = fi & 7;
            int m = mbase + row;
            float4 v = make_float4(0.f, 0.f, 0.f, 0.f);
            if (m < M) v = *(const float4*)&A[(size_t)m * K + kc + cf * 4];
            As[cf * 4 + 0][row] = v.x; As[cf * 4 + 1][row] = v.y;
            As[cf * 4 + 2][row] = v.z; As[cf * 4 + 3][row] = v.w;
        }
        #pragma unroll
        for (int i = 0; i < 6; ++i) {
            int fi = tid + 256 * i;
            int g = fi >> 3, cf = fi & 7;
            const float* Wsel = (g < 96) ? (Wf + (size_t)g * K)
                                         : (Wb + (size_t)(g - 96) * K);
            float4 v = *(const float4*)&Wsel[kc + cf * 4];
            Bs[cf * 4 + 0][g] = v.x; Bs[cf * 4 + 1][g] = v.y;
            Bs[cf * 4 + 2][g] = v.z; Bs[cf * 4 + 3][g] = v.w;
        }
        __syncthreads();
        #pragma unroll
        for (int k = 0; k < GEMM_KC; ++k) {
            float a[8], bb[6];
            *(float4*)&a[0] = *(const float4*)&As[k][m_off];
            *(float4*)&a[4] = *(const float4*)&As[k][m_off + 4];
            *(float2*)&bb[0] = *(const float2*)&Bs[k][n_off];
            *(float2*)&bb[2] = *(const float2*)&Bs[k][n_off + 2];
            *(float2*)&bb[4] = *(const float2*)&Bs[k][n_off + 4];
            #pragma unroll
            for (int r = 0; r < 8; ++r)
                #pragma unroll
                for (int c = 0; c < 6; ++c)
                    acc[r][c] = fmaf(a[r], bb[c], acc[r][c]);
        }
        __syncthreads();
    }

    float bias[6], gsc[6];
    #pragma unroll
    for (int c = 0; c < 6; ++c) {
        int g = n_off + c;
        int g96 = (g < 96) ? g : g - 96;
        const float* bih = (g < 96) ? bihf : bihb;
        const float* bhh = (g < 96) ? bhhf : bhhb;
        bias[c] = bih[g96] + ((g96 < 64) ? bhh[g96] : 0.f);
        gsc[c]  = (g96 < 64) ? -LOG2E_F : 2.0f * LOG2E_F;
    }
    #pragma unroll
    for (int r = 0; r < 8; ++r) {
        int m = mbase + m_off + r;
        if (m < M) {
            float* op = &Out[(size_t)m * 192 + n_off];
            #pragma unroll
            for (int c = 0; c < 6; ++c) op[c] = (acc[r][c] + bias[c]) * gsc[c];
        }
    }
}

// ---------------------------------------------------------------------------
// GRU scan, K-split layout (r4 structure — best measured) with a SHORTER
// per-step spine. r5 falsified the memory-latency theory (LDS-only loop was
// not faster), so C (~720cy/step) is the arithmetic dependency chain. This
// round trims it:
//   - k-half combine via permlane-PAIR-SUM (xsum32): {self,swapped} pair
//     summed directly — deletes the 2-xor fold (bit-identical result).
//   - matvec accumulators split 4+4 (+v_pk_add): chain depth 32->24 cy.
//   - yn as a single fused fma(r, hns, cN); seed fold -> v_xor3.
// Everything else (layout, prefetch, pin, launch config) identical to r4:
// rows [L,H,L,H], lane l & l^32 compute complementary k-halves of the same
// unit (48 weight VGPRs), seed via permlane16_swap, 15-op DPP butterfly,
// exp2/rcp activations with log2e pre-folded, 2-bank 4-step gi prefetch.
// ---------------------------------------------------------------------------
template <int USE_IDS>
__global__ __launch_bounds__(64, 1)
__attribute__((amdgpu_waves_per_eu(1, 1)))
void gru_scan(
    const float* __restrict__ gi,     // [rows,192]: G0 (gather) or gi1 (direct)
    const int* __restrict__ ids,
    const int* __restrict__ mask,
    const float* __restrict__ Whh_f, const float* __restrict__ Whh_b,
    const float* __restrict__ bhh_f, const float* __restrict__ bhh_b,
    float* __restrict__ out_seq,      // [B,T,64] or nullptr
    float* __restrict__ out_fin)      // [B,64]   or nullptr
{
    const int l = threadIdx.x;
    const int i16 = l & 15;
    const int row = l >> 4;
    const int hi = row & 1;               // unit half
    const int kh = row >> 1;              // k half this lane computes
    const int j = i16 + 16 * hi;          // this lane's unit
    const bool lower = l < 32;            // lanes 0-31: j == l
    const bool self_seed = (hi == kh);    // rows 0,3 own their k-half seed
    const int dir = blockIdx.x & 1;
    const int b = blockIdx.x >> 1;
    const int bT = b * T_;

    const float* Whh = dir ? Whh_b : Whh_f;
    const float* bhh = dir ? bhh_b : bhh_f;

    const float sRZ = -LOG2E_F;
    const float sN2 = 2.0f * LOG2E_F;

    // butterfly value order: pair q holds seed[i16^M0[q]], seed[i16^M1[q]]
    const int M0[8] = {0, 2, 7, 5, 15, 13, 8, 10};
    const int M1[8] = {1, 3, 6, 4, 14, 12, 9, 11};

    v2f wR[8], wZ[8], wN[8];
    #pragma unroll
    for (int q = 0; q < 8; ++q) {
        const int c0 = kh * 16 + (i16 ^ M0[q]);
        const int c1 = kh * 16 + (i16 ^ M1[q]);
        wR[q] = (v2f){Whh[j * 32 + c0] * sRZ, Whh[j * 32 + c1] * sRZ};
        wZ[q] = (v2f){Whh[(32 + j) * 32 + c0] * sRZ,
                      Whh[(32 + j) * 32 + c1] * sRZ};
        wN[q] = (v2f){Whh[(64 + j) * 32 + c0] * sN2,
                      Whh[(64 + j) * 32 + c1] * sN2};
    }
    float bns = bhh[64 + j] * sN2;

    // PIN: opaque asm keeps the 48 weight regs loop-resident (no remat).
    #pragma unroll
    for (int q = 0; q < 8; ++q)
        asm volatile("" : "+v"(wR[q]), "+v"(wZ[q]), "+v"(wN[q]));
    asm volatile("" : "+v"(bns));

    const int offR = dir * 96 + j;
    const int offZ = dir * 96 + 32 + j;
    const int offN = dir * 96 + 64 + j;

    // int4 word base for chunk c (fwd: t=4c..4c+3; bwd: t=511-4c..508-4c)
    auto wbase = [&](int c) { return dir ? (bT + 508 - 4 * c) : (bT + 4 * c); };

    // ---- prologue ----
    int4 ids0 = make_int4(0, 0, 0, 0);
    if (USE_IDS) ids0 = *(const int4*)&ids[wbase(0)];
    int4 mask_use = *(const int4*)&mask[wbase(0)];
    int4 mask_mid = *(const int4*)&mask[wbase(1)];
    int4 mask_in  = make_int4(0, 0, 0, 0);
    int4 ids_pf = make_int4(0, 0, 0, 0), ids_mid = ids_pf, ids_in = ids_pf;
    if (USE_IDS) {
        ids_pf  = *(const int4*)&ids[wbase(1)];
        ids_mid = *(const int4*)&ids[wbase(2)];
    }

    float gR[2][4], gZ[2][4], gN[2][4];
    #pragma unroll
    for (int u = 0; u < 4; ++u) {
        int rowi;
        if (USE_IDS) {
            const int* ip = (const int*)&ids0;
            rowi = dir ? ip[3 - u] : ip[u];
        } else {
            rowi = bT + (dir ? (511 - u) : u);
        }
        const float* gp = gi + (size_t)rowi * 192;
        gR[0][u] = gp[offR];
        gZ[0][u] = gp[offZ];
        gN[0][u] = gp[offN];
    }

    float h = 0.f;

    for (int c2 = 0; c2 < 64; ++c2) {
        #pragma unroll
        for (int pb = 0; pb < 2; ++pb) {
            const int c = 2 * c2 + pb;
            // far prefetch: ids for chunk c+3, mask for chunk c+2 (clamped)
            if (USE_IDS) {
                const int ci = (c + 3 < 128) ? (c + 3) : 127;
                ids_in = *(const int4*)&ids[wbase(ci)];
            }
            {
                const int cm = (c + 2 < 128) ? (c + 2) : 127;
                mask_in = *(const int4*)&mask[wbase(cm)];
            }
            const int cN = (c + 1 < 128) ? (c + 1) : 127;  // gi prefetch chunk

            #pragma unroll
            for (int u = 0; u < 4; ++u) {
                // --- issue gi prefetch for chunk c+1, body u, into bank pb^1
                int rowN;
                if (USE_IDS) {
                    const int* ip = (const int*)&ids_pf;
                    rowN = dir ? ip[3 - u] : ip[u];
                } else {
                    rowN = bT + (dir ? (511 - 4 * cN - u) : (4 * cN + u));
                }
                const float* gpN = gi + (size_t)rowN * 192;
                gR[pb ^ 1][u] = gpN[offR];
                gZ[pb ^ 1][u] = gpN[offZ];
                gN[pb ^ 1][u] = gpN[offN];

                // --- compute step (gi bank pb, loaded during chunk c-1)
                const int* mu = (const int*)&mask_use;
                const int m = dir ? mu[3 - u] : mu[u];

                // seed = h of (kh*16 + i16): rows 0,3 self; rows 1,2 from l^16
                const float hx = swap16(h);
                const float seed = self_seed ? h : hx;

                // distribute 16 seed values within the row (15 DPP movs)
                v2f p[8];
                p[0].x = seed;                      p[0].y = mdpp<DPP_XOR1>(seed);
                p[1].x = mdpp<DPP_XOR2>(seed);      p[1].y = mdpp<DPP_XOR3>(seed);
                p[2].x = mdpp<DPP_XOR7>(seed);      p[2].y = mdpp<DPP_XOR7>(p[0].y);
                p[3].x = mdpp<DPP_XOR7>(p[1].x);    p[3].y = mdpp<DPP_XOR7>(p[1].y);
                p[4].x = mdpp<DPP_XOR15>(seed);     p[4].y = mdpp<DPP_XOR15>(p[0].y);
                p[5].x = mdpp<DPP_XOR15>(p[1].x);   p[5].y = mdpp<DPP_XOR15>(p[1].y);
                p[6].x = mdpp<DPP_XOR15>(p[2].x);   p[6].y = mdpp<DPP_XOR15>(p[2].y);
                p[7].x = mdpp<DPP_XOR15>(p[3].x);   p[7].y = mdpp<DPP_XOR15>(p[3].y);

                // half-K matvec: 3 gates x (4+4)-split pk_fma chains
                v2f aR0 = {0.f, 0.f}, aZ0 = {0.f, 0.f}, aN0 = {0.f, 0.f};
                v2f aR1 = {0.f, 0.f}, aZ1 = {0.f, 0.f}, aN1 = {0.f, 0.f};
                #pragma unroll
                for (int q = 0; q < 4; ++q) {
                    pk_fma(aR0, wR[q], p[q]);
                    pk_fma(aZ0, wZ[q], p[q]);
                    pk_fma(aN0, wN[q], p[q]);
                }
                #pragma unroll
                for (int q = 4; q < 8; ++q) {
                    pk_fma(aR1, wR[q], p[q]);
                    pk_fma(aZ1, wZ[q], p[q]);
                    pk_fma(aN1, wN[q], p[q]);
                }
                const v2f aR = aR0 + aR1;   // v_pk_add_f32
                const v2f aZ = aZ0 + aZ1;
                const v2f aN = aN0 + aN1;

                // combine k-halves: pair-sum over lanes l, l^32 (same unit)
                const float SR = xsum32(aR.x + aR.y);
                const float SZ = xsum32(aZ.x + aZ.y);
                const float SN = xsum32(aN.x + aN.y);

                const float yr  = gR[pb][u] + SR;
                const float yz  = gZ[pb][u] + SZ;
                const float hns = bns + SN;
                const float r = rcp_fast(1.0f + exp2_fast(yr));
                const float z = rcp_fast(1.0f + exp2_fast(yz));
                const float yn = fmaf(r, hns, gN[pb][u]);
                const float n = fmaf(-2.0f, rcp_fast(1.0f + exp2_fast(yn)), 1.0f);
                const float hnew = n + z * (h - n);      // (1-z)n + z h
                h = m ? hnew : h;                        // packed-seq freeze

                if (out_seq != nullptr) {
                    const int t = dir ? (511 - 4 * c - u) : (4 * c + u);
                    if (lower)
                        out_seq[(size_t)(bT + t) * 64 + dir * 32 + j] = h;
                }
            }
            // --- rotate chunk-granular prefetch regs (1-chunk distance)
            mask_use = mask_mid; mask_mid = mask_in;
            if (USE_IDS) { ids_pf = ids_mid; ids_mid = ids_in; }
        }
    }

    if (out_fin != nullptr && lower)
        out_fin[b * 64 + dir * 32 + j] = h;
}

// ---------------------------------------------------------------------------
// Head: out[b,o] = hfin[b,:] . Wout[o,:] + bout[o]
// ---------------------------------------------------------------------------
__global__ void head_kernel(const float* __restrict__ hfin,
                            const float* __restrict__ Wout,
                            const float* __restrict__ bout,
                            float* __restrict__ out)
{
    int idx = blockIdx.x * blockDim.x + threadIdx.x;
    if (idx >= B_ * 6) return;
    int b = idx / 6, o = idx % 6;
    float acc = bout[o];
    const float* hp = hfin + b * 64;
    const float* wp = Wout + o * 64;
    #pragma unroll
    for (int k = 0; k < 64; ++k) acc = fmaf(hp[k], wp[k], acc);
    out[idx] = acc;
}

// ---------------------------------------------------------------------------
extern "C" void kernel_launch(void* const* d_in, const int* in_sizes, int n_in,
                              void* d_out, int out_size, void* d_ws, size_t ws_size,
                              hipStream_t stream)
{
    const int*   ids   = (const int*)d_in[0];
    const int*   mask  = (const int*)d_in[1];
    const float* embed = (const float*)d_in[2];
    const float* Wih0f = (const float*)d_in[3];
    const float* Whh0f = (const float*)d_in[4];
    const float* bih0f = (const float*)d_in[5];
    const float* bhh0f = (const float*)d_in[6];
    const float* Wih0b = (const float*)d_in[7];
    const float* Whh0b = (const float*)d_in[8];
    const float* bih0b = (const float*)d_in[9];
    const float* bhh0b = (const float*)d_in[10];
    const float* Wih1f = (const float*)d_in[11];
    const float* Whh1f = (const float*)d_in[12];
    const float* bih1f = (const float*)d_in[13];
    const float* bhh1f = (const float*)d_in[14];
    const float* Wih1b = (const float*)d_in[15];
    const float* Whh1b = (const float*)d_in[16];
    const float* bih1b = (const float*)d_in[17];
    const float* bhh1b = (const float*)d_in[18];
    const float* Wout  = (const float*)d_in[19];
    const float* bout  = (const float*)d_in[20];

    // workspace layout (floats):
    //   gbuf : G0 [V,192] (K1,K2) then gi1 [B*T,192] (K3,K4)
    //   x1   : [B,T,64]
    //   hfin : [B,64]
    float* ws   = (float*)d_ws;
    float* gbuf = ws;
    float* x1   = ws + (size_t)B_ * T_ * 192;
    float* hfin = x1 + (size_t)B_ * T_ * 64;

    // K1: vocab-factored layer-0 input gates  G0 = (embed @ Wcat0^T + b) * gsc
    gemm_gates<<<(V_ + GEMM_MT - 1) / GEMM_MT, 256, 0, stream>>>(
        embed, V_, E_, Wih0f, Wih0b, bih0f, bhh0f, bih0b, bhh0b, gbuf);

    // K2: layer-0 bidirectional scan (gathers G0[id]), writes x1
    gru_scan<1><<<2 * B_, 64, 0, stream>>>(
        gbuf, ids, mask, Whh0f, Whh0b, bhh0f, bhh0b, x1, nullptr);

    // K3: layer-1 input gates  gi1 = (x1 @ Wcat1^T + b) * gsc
    gemm_gates<<<(B_ * T_) / GEMM_MT, 256, 0, stream>>>(
        x1, B_ * T_, 64, Wih1f, Wih1b, bih1f, bhh1f, bih1b, bhh1b, gbuf);

    // K4: layer-1 scan, final hiddens only
    gru_scan<0><<<2 * B_, 64, 0, stream>>>(
        gbuf, nullptr, mask, Whh1f, Whh1b, bhh1f, bhh1b, nullptr, hfin);

    // K5: output head
    head_kernel<<<(B_ * 6 + 255) / 256, 256, 0, stream>>>(hfin, Wout, bout,
                                                          (float*)d_out);
}

// Round 8
// 469.240 us; speedup vs baseline: 1.0651x; 1.0314x over previous
//
#include <hip/hip_runtime.h>
#include <hip/hip_bf16.h>
#include <stdint.h>

#define B_ 256
#define T_ 512
#define V_ 30000
#define E_ 256
#define H_ 32

typedef float v2f __attribute__((ext_vector_type(2)));
typedef unsigned int uint2e __attribute__((ext_vector_type(2)));

#define LOG2E_F 1.44269504088896340736f

// ---------------------------------------------------------------------------
// Raw-ISA helpers
// ---------------------------------------------------------------------------
__device__ __forceinline__ float exp2_fast(float x) {      // 2^x
    float r; asm("v_exp_f32 %0, %1" : "=v"(r) : "v"(x)); return r;
}
__device__ __forceinline__ float rcp_fast(float x) {       // 1/x
    float r; asm("v_rcp_f32 %0, %1" : "=v"(r) : "v"(x)); return r;
}
// packed fp32 FMA, all-VGPR operands: acc.{lo,hi} += w.{lo,hi} * h.{lo,hi}
__device__ __forceinline__ void pk_fma(v2f& acc, v2f w, v2f h) {
    asm("v_pk_fma_f32 %0, %1, %2, %0" : "+v"(acc) : "v"(w), "v"(h));
}
// DPP lane-permute move (XOR patterns only -> direction-unambiguous)
template <int CTRL>
__device__ __forceinline__ float mdpp(float x) {
    return __int_as_float(
        __builtin_amdgcn_mov_dpp(__float_as_int(x), CTRL, 0xF, 0xF, true));
}
#define DPP_XOR1  0xB1   // quad_perm [1,0,3,2]
#define DPP_XOR2  0x4E   // quad_perm [2,3,0,1]
#define DPP_XOR3  0x1B   // quad_perm [3,2,1,0]
#define DPP_XOR7  0x141  // row_half_mirror  (i -> i^7 within 8)
#define DPP_XOR15 0x140  // row_mirror       (i -> i^15 within 16)

// x[l] + x[l^32]: permlane32_swap(x,x) yields the pair {x[l], x[l^32]} per
// lane -> sum is exact and order-free (IEEE add commutative).
__device__ __forceinline__ float xsum32(float x) {
    uint2e r = __builtin_amdgcn_permlane32_swap(
        __float_as_uint(x), __float_as_uint(x), false, false);
    return __uint_as_float(r.x) + __uint_as_float(r.y);
}
// value of x at lane (l ^ 16): exact via xor-fold of the {self,swapped} pair
__device__ __forceinline__ float swap16(float x) {
    uint2e r = __builtin_amdgcn_permlane16_swap(
        __float_as_uint(x), __float_as_uint(x), false, false);
    return __uint_as_float(r.x ^ r.y ^ __float_as_uint(x));
}

// ---------------------------------------------------------------------------
// GEMM: Out[M,192] = (A[M,K] @ Wcat[192,K]^T + bias) * gate_scale
// gate_scale folds the exp->exp2 conversion: r,z gates * -log2e ; n * +2log2e
// ---------------------------------------------------------------------------
#define GEMM_MT 64
#define GEMM_KC 32
#define GEMM_PA 68
#define GEMM_PB 196

__global__ __launch_bounds__(256) void gemm_gates(
    const float* __restrict__ A, int M, int K,
    const float* __restrict__ Wf, const float* __restrict__ Wb,
    const float* __restrict__ bihf, const float* __restrict__ bhhf,
    const float* __restrict__ bihb, const float* __restrict__ bhhb,
    float* __restrict__ Out)
{
    __shared__ float As[GEMM_KC][GEMM_PA];
    __shared__ float Bs[GEMM_KC][GEMM_PB];

    const int tid = threadIdx.x;
    const int mbase = blockIdx.x * GEMM_MT;
    const int mg = tid >> 5, ng = tid & 31;
    const int m_off = mg * 8, n_off = ng * 6;

    float acc[8][6];
    #pragma unroll
    for (int r = 0; r < 8; ++r)
        #pragma unroll
        for (int c = 0; c < 6; ++c) acc[r][c] = 0.f;

    for (int kc = 0; kc < K; kc += GEMM_KC) {
        #pragma unroll
        for (int i = 0; i < 2; ++i) {
            int fi = tid + 256 * i;
            int row = fi >> 3, cf = fi & 7;
            int m = mbase + row;
            float4 v = make_float4(0.f, 0.f, 0.f, 0.f);
            if (m < M) v = *(const float4*)&A[(size_t)m * K + kc + cf * 4];
            As[cf * 4 + 0][row] = v.x; As[cf * 4 + 1][row] = v.y;
            As[cf * 4 + 2][row] = v.z; As[cf * 4 + 3][row] = v.w;
        }
        #pragma unroll
        for (int i = 0; i < 6; ++i) {
            int fi = tid + 256 * i;
            int g = fi >> 3, cf = fi & 7;
            const float* Wsel = (g < 96) ? (Wf + (size_t)g * K)
                                         : (Wb + (size_t)(g - 96) * K);
            float4 v = *(const float4*)&Wsel[kc + cf * 4];
            Bs[cf * 4 + 0][g] = v.x; Bs[cf * 4 + 1][g] = v.y;
            Bs[cf * 4 + 2][g] = v.z; Bs[cf * 4 + 3][g] = v.w;
        }
        __syncthreads();
        #pragma unroll
        for (int k = 0; k < GEMM_KC; ++k) {
            float a[8], bb[6];
            *(float4*)&a[0] = *(const float4*)&As[k][m_off];
            *(float4*)&a[4] = *(const float4*)&As[k][m_off + 4];
            *(float2*)&bb[0] = *(const float2*)&Bs[k][n_off];
            *(float2*)&bb[2] = *(const float2*)&Bs[k][n_off + 2];
            *(float2*)&bb[4] = *(const float2*)&Bs[k][n_off + 4];
            #pragma unroll
            for (int r = 0; r < 8; ++r)
                #pragma unroll
                for (int c = 0; c < 6; ++c)
                    acc[r][c] = fmaf(a[r], bb[c], acc[r][c]);
        }
        __syncthreads();
    }

    float bias[6], gsc[6];
    #pragma unroll
    for (int c = 0; c < 6; ++c) {
        int g = n_off + c;
        int g96 = (g < 96) ? g : g - 96;
        const float* bih = (g < 96) ? bihf : bihb;
        const float* bhh = (g < 96) ? bhhf : bhhb;
        bias[c] = bih[g96] + ((g96 < 64) ? bhh[g96] : 0.f);
        gsc[c]  = (g96 < 64) ? -LOG2E_F : 2.0f * LOG2E_F;
    }
    #pragma unroll
    for (int r = 0; r < 8; ++r) {
        int m = mbase + m_off + r;
        if (m < M) {
            float* op = &Out[(size_t)m * 192 + n_off];
            #pragma unroll
            for (int c = 0; c < 6; ++c) op[c] = (acc[r][c] + bias[c]) * gsc[c];
        }
    }
}

// ---------------------------------------------------------------------------
// GRU scan, K-split layout. r7 post-mortem: VGPR_Count=52 < the 48 declared
// weight regs alone -> the pinned weights were parked OUTSIDE arch VGPRs
// (AGPR/scratch) and re-read ~48x EVERY step. Cross-round check: r3 (96
// weight regs) -> r4 (48) saved 88cy/step ~= 48 reads x 2cy. THIS round
// shrinks total register demand so everything fits in arch VGPRs:
//   - gi prefetch: 2-step chunks, 2 banks -> 12 regs (was 24)
//   - masks: per-32-step __ballot -> SGPR bit-tests (was 12 VGPRs + VALU)
//   - ids: int2 x2 -> 4 regs (was 12)
//   - weights pinned at init AND kept alive per segment (in-loop "+v"
//     keepalive: if the allocator still parks them it must copy 16x less
//     often; with demand ~100 regs it should keep them resident)
// Step arithmetic is byte-identical to r7 (bit-identical output).
// ---------------------------------------------------------------------------
template <int USE_IDS>
__global__ __launch_bounds__(64, 1)
__attribute__((amdgpu_waves_per_eu(1, 1)))
void gru_scan(
    const float* __restrict__ gi,     // [rows,192]: G0 (gather) or gi1 (direct)
    const int* __restrict__ ids,
    const int* __restrict__ mask,
    const float* __restrict__ Whh_f, const float* __restrict__ Whh_b,
    const float* __restrict__ bhh_f, const float* __restrict__ bhh_b,
    float* __restrict__ out_seq,      // [B,T,64] or nullptr
    float* __restrict__ out_fin)      // [B,64]   or nullptr
{
    const int l = threadIdx.x;
    const int i16 = l & 15;
    const int row = l >> 4;
    const int hi = row & 1;               // unit half
    const int kh = row >> 1;              // k half this lane computes
    const int j = i16 + 16 * hi;          // this lane's unit
    const bool lower = l < 32;            // lanes 0-31: j == l
    const bool self_seed = (hi == kh);    // rows 0,3 own their k-half seed
    const int dir = blockIdx.x & 1;
    const int b = blockIdx.x >> 1;
    const int bT = b * T_;

    const float* Whh = dir ? Whh_b : Whh_f;
    const float* bhh = dir ? bhh_b : bhh_f;

    const float sRZ = -LOG2E_F;
    const float sN2 = 2.0f * LOG2E_F;

    // butterfly value order: pair q holds seed[i16^M0[q]], seed[i16^M1[q]]
    const int M0[8] = {0, 2, 7, 5, 15, 13, 8, 10};
    const int M1[8] = {1, 3, 6, 4, 14, 12, 9, 11};

    v2f wR[8], wZ[8], wN[8];
    #pragma unroll
    for (int q = 0; q < 8; ++q) {
        const int c0 = kh * 16 + (i16 ^ M0[q]);
        const int c1 = kh * 16 + (i16 ^ M1[q]);
        wR[q] = (v2f){Whh[j * 32 + c0] * sRZ, Whh[j * 32 + c1] * sRZ};
        wZ[q] = (v2f){Whh[(32 + j) * 32 + c0] * sRZ,
                      Whh[(32 + j) * 32 + c1] * sRZ};
        wN[q] = (v2f){Whh[(64 + j) * 32 + c0] * sN2,
                      Whh[(64 + j) * 32 + c1] * sN2};
    }
    float bns = bhh[64 + j] * sN2;

    // PIN at init: loads cannot be sunk into the loop.
    #pragma unroll
    for (int q = 0; q < 8; ++q)
        asm volatile("" : "+v"(wR[q]), "+v"(wZ[q]), "+v"(wN[q]));
    asm volatile("" : "+v"(bns));

    const int offR = dir * 96 + j;     // offZ = offR+32, offN = offR+64

    // logical step n = 0..511 maps to time t = dir ? T-1-n : n
    auto t_of = [&](int n) { return dir ? (T_ - 1 - n) : n; };
    // int2 word base for 2-step chunk c
    auto cbase = [&](int c) { return dir ? (bT + 510 - 2 * c) : (bT + 2 * c); };

    // ---- prologue ----
    // masks: raw value for seg 0/1 (lane l<32 holds step l of the segment)
    int mk_cur = lower ? mask[bT + t_of(l)] : 0;
    int mk_nxt = lower ? mask[bT + t_of(32 + l)] : 0;

    int2 ids_pf = make_int2(0, 0), ids_in = make_int2(0, 0);
    float gR[2][2], gZ[2][2], gN[2][2];
    {
        int ra, rb;
        if (USE_IDS) {
            const int2 i0 = *(const int2*)&ids[cbase(0)];
            ra = dir ? i0.y : i0.x;
            rb = dir ? i0.x : i0.y;
            ids_pf = *(const int2*)&ids[cbase(1)];
        } else {
            ra = bT + t_of(0);
            rb = bT + t_of(1);
        }
        const float* ga = gi + (size_t)ra * 192 + offR;
        const float* gb = gi + (size_t)rb * 192 + offR;
        gR[0][0] = ga[0]; gZ[0][0] = ga[32]; gN[0][0] = ga[64];
        gR[0][1] = gb[0]; gZ[0][1] = gb[32]; gN[0][1] = gb[64];
    }

    float h = 0.f;

    for (int seg = 0; seg < 16; ++seg) {
        // keepalive: weights must be arch-VGPR-resident here (16x/kernel)
        #pragma unroll
        for (int q = 0; q < 8; ++q)
            asm volatile("" : "+v"(wR[q]), "+v"(wZ[q]), "+v"(wN[q]));

        const uint32_t mseg = (uint32_t)__ballot(mk_cur != 0);
        mk_cur = mk_nxt;
        {
            const int ms = (seg + 2 < 16) ? (seg + 2) : 15;
            mk_nxt = lower ? mask[bT + t_of(32 * ms + l)] : 0;
        }

        for (int ch2 = 0; ch2 < 8; ++ch2) {
            const int cc0 = seg * 16 + 2 * ch2;
            #pragma unroll
            for (int pb = 0; pb < 2; ++pb) {     // two chunks: banks 0,1
                const int cc = cc0 + pb;
                // ids prefetch for chunk cc+2 (consumed next chunk)
                if (USE_IDS) {
                    const int ci = (cc + 2 < 256) ? (cc + 2) : 255;
                    ids_in = *(const int2*)&ids[cbase(ci)];
                }
                // gi prefetch for chunk cc+1 -> bank pb^1
                {
                    int ra, rb;
                    if (USE_IDS) {
                        ra = dir ? ids_pf.y : ids_pf.x;
                        rb = dir ? ids_pf.x : ids_pf.y;
                    } else {
                        const int cg = (cc + 1 < 256) ? (cc + 1) : 255;
                        ra = bT + t_of(2 * cg);
                        rb = bT + t_of(2 * cg + 1);
                    }
                    const float* ga = gi + (size_t)ra * 192 + offR;
                    const float* gb = gi + (size_t)rb * 192 + offR;
                    gR[pb ^ 1][0] = ga[0]; gZ[pb ^ 1][0] = ga[32]; gN[pb ^ 1][0] = ga[64];
                    gR[pb ^ 1][1] = gb[0]; gZ[pb ^ 1][1] = gb[32]; gN[pb ^ 1][1] = gb[64];
                }

                #pragma unroll
                for (int u = 0; u < 2; ++u) {
                    const int su = 4 * ch2 + 2 * pb + u;   // step within segment

                    // seed = h of (kh*16+i16): rows 0,3 self; rows 1,2 via l^16
                    const float hx = swap16(h);
                    const float seed = self_seed ? h : hx;

                    // distribute 16 seed values within the row (15 DPP movs)
                    v2f p[8];
                    p[0].x = seed;                      p[0].y = mdpp<DPP_XOR1>(seed);
                    p[1].x = mdpp<DPP_XOR2>(seed);      p[1].y = mdpp<DPP_XOR3>(seed);
                    p[2].x = mdpp<DPP_XOR7>(seed);      p[2].y = mdpp<DPP_XOR7>(p[0].y);
                    p[3].x = mdpp<DPP_XOR7>(p[1].x);    p[3].y = mdpp<DPP_XOR7>(p[1].y);
                    p[4].x = mdpp<DPP_XOR15>(seed);     p[4].y = mdpp<DPP_XOR15>(p[0].y);
                    p[5].x = mdpp<DPP_XOR15>(p[1].x);   p[5].y = mdpp<DPP_XOR15>(p[1].y);
                    p[6].x = mdpp<DPP_XOR15>(p[2].x);   p[6].y = mdpp<DPP_XOR15>(p[2].y);
                    p[7].x = mdpp<DPP_XOR15>(p[3].x);   p[7].y = mdpp<DPP_XOR15>(p[3].y);

                    // half-K matvec: 3 gates x (4+4)-split pk_fma chains
                    v2f aR0 = {0.f, 0.f}, aZ0 = {0.f, 0.f}, aN0 = {0.f, 0.f};
                    v2f aR1 = {0.f, 0.f}, aZ1 = {0.f, 0.f}, aN1 = {0.f, 0.f};
                    #pragma unroll
                    for (int q = 0; q < 4; ++q) {
                        pk_fma(aR0, wR[q], p[q]);
                        pk_fma(aZ0, wZ[q], p[q]);
                        pk_fma(aN0, wN[q], p[q]);
                    }
                    #pragma unroll
                    for (int q = 4; q < 8; ++q) {
                        pk_fma(aR1, wR[q], p[q]);
                        pk_fma(aZ1, wZ[q], p[q]);
                        pk_fma(aN1, wN[q], p[q]);
                    }
                    const v2f aR = aR0 + aR1;   // v_pk_add_f32
                    const v2f aZ = aZ0 + aZ1;
                    const v2f aN = aN0 + aN1;

                    // combine k-halves: pair-sum over lanes l, l^32 (same unit)
                    const float SR = xsum32(aR.x + aR.y);
                    const float SZ = xsum32(aZ.x + aZ.y);
                    const float SN = xsum32(aN.x + aN.y);

                    const float yr  = gR[pb][u] + SR;
                    const float yz  = gZ[pb][u] + SZ;
                    const float hns = bns + SN;
                    const float r = rcp_fast(1.0f + exp2_fast(yr));
                    const float z = rcp_fast(1.0f + exp2_fast(yz));
                    const float yn = fmaf(r, hns, gN[pb][u]);
                    const float n = fmaf(-2.0f, rcp_fast(1.0f + exp2_fast(yn)), 1.0f);
                    const float hnew = n + z * (h - n);      // (1-z)n + z h
                    const bool mm = (mseg >> su) & 1u;       // SGPR bit-test
                    h = mm ? hnew : h;                       // packed-seq freeze

                    if (out_seq != nullptr && lower) {
                        const int t = t_of(32 * seg + su);
                        out_seq[(size_t)(bT + t) * 64 + dir * 32 + j] = h;
                    }
                }
                if (USE_IDS) ids_pf = ids_in;   // rotate (1-chunk distance)
            }
        }
    }

    if (out_fin != nullptr && lower)
        out_fin[b * 64 + dir * 32 + j] = h;
}

// ---------------------------------------------------------------------------
// Head: out[b,o] = hfin[b,:] . Wout[o,:] + bout[o]
// ---------------------------------------------------------------------------
__global__ void head_kernel(const float* __restrict__ hfin,
                            const float* __restrict__ Wout,
                            const float* __restrict__ bout,
                            float* __restrict__ out)
{
    int idx = blockIdx.x * blockDim.x + threadIdx.x;
    if (idx >= B_ * 6) return;
    int b = idx / 6, o = idx % 6;
    float acc = bout[o];
    const float* hp = hfin + b * 64;
    const float* wp = Wout + o * 64;
    #pragma unroll
    for (int k = 0; k < 64; ++k) acc = fmaf(hp[k], wp[k], acc);
    out[idx] = acc;
}

// ---------------------------------------------------------------------------
extern "C" void kernel_launch(void* const* d_in, const int* in_sizes, int n_in,
                              void* d_out, int out_size, void* d_ws, size_t ws_size,
                              hipStream_t stream)
{
    const int*   ids   = (const int*)d_in[0];
    const int*   mask  = (const int*)d_in[1];
    const float* embed = (const float*)d_in[2];
    const float* Wih0f = (const float*)d_in[3];
    const float* Whh0f = (const float*)d_in[4];
    const float* bih0f = (const float*)d_in[5];
    const float* bhh0f = (const float*)d_in[6];
    const float* Wih0b = (const float*)d_in[7];
    const float* Whh0b = (const float*)d_in[8];
    const float* bih0b = (const float*)d_in[9];
    const float* bhh0b = (const float*)d_in[10];
    const float* Wih1f = (const float*)d_in[11];
    const float* Whh1f = (const float*)d_in[12];
    const float* bih1f = (const float*)d_in[13];
    const float* bhh1f = (const float*)d_in[14];
    const float* Wih1b = (const float*)d_in[15];
    const float* Whh1b = (const float*)d_in[16];
    const float* bih1b = (const float*)d_in[17];
    const float* bhh1b = (const float*)d_in[18];
    const float* Wout  = (const float*)d_in[19];
    const float* bout  = (const float*)d_in[20];

    // workspace layout (floats):
    //   gbuf : G0 [V,192] (K1,K2) then gi1 [B*T,192] (K3,K4)
    //   x1   : [B,T,64]
    //   hfin : [B,64]
    float* ws   = (float*)d_ws;
    float* gbuf = ws;
    float* x1   = ws + (size_t)B_ * T_ * 192;
    float* hfin = x1 + (size_t)B_ * T_ * 64;

    // K1: vocab-factored layer-0 input gates  G0 = (embed @ Wcat0^T + b) * gsc
    gemm_gates<<<(V_ + GEMM_MT - 1) / GEMM_MT, 256, 0, stream>>>(
        embed, V_, E_, Wih0f, Wih0b, bih0f, bhh0f, bih0b, bhh0b, gbuf);

    // K2: layer-0 bidirectional scan (gathers G0[id]), writes x1
    gru_scan<1><<<2 * B_, 64, 0, stream>>>(
        gbuf, ids, mask, Whh0f, Whh0b, bhh0f, bhh0b, x1, nullptr);

    // K3: layer-1 input gates  gi1 = (x1 @ Wcat1^T + b) * gsc
    gemm_gates<<<(B_ * T_) / GEMM_MT, 256, 0, stream>>>(
        x1, B_ * T_, 64, Wih1f, Wih1b, bih1f, bhh1f, bih1b, bhh1b, gbuf);

    // K4: layer-1 scan, final hiddens only
    gru_scan<0><<<2 * B_, 64, 0, stream>>>(
        gbuf, nullptr, mask, Whh1f, Whh1b, bhh1f, bhh1b, nullptr, hfin);

    // K5: output head
    head_kernel<<<(B_ * 6 + 255) / 256, 256, 0, stream>>>(hfin, Wout, bout,
                                                          (float*)d_out);
}